// Round 8
// baseline (1850.639 us; speedup 1.0000x reference)
//
#include <hip/hip_runtime.h>
#include <cstdint>

#define HSZ 32
#define TSTEPS 256
#define ISZ 6

// sigmoid(x) = 1/(1+e^-x); tanh(x) = 2*sigmoid(2x)-1. Native v_exp/v_rcp.
__device__ __forceinline__ float fast_sigmoid(float x) {
    return __builtin_amdgcn_rcpf(1.0f + __expf(-x));
}
__device__ __forceinline__ float fast_tanh(float x) {
    return 2.0f * __builtin_amdgcn_rcpf(1.0f + __expf(-2.0f * x)) - 1.0f;
}

// Mapping: block = 256 threads = 4 waves; each wave handles 2 batch elements
// (lanes 0-31 -> elem A, lanes 32-63 -> elem B); lane j = hidden unit j.
// Each lane keeps its 4 gate rows of W_hh/W_ih in VGPRs, h/c in regs; h is
// broadcast per step via LDS (1 ds_write + 8 broadcast ds_read_b128,
// wave-synchronous, no __syncthreads in the T-loop).
//
// launch_bounds(256,4): grid is exactly 4 blocks/CU (1024/256); at (256,2) the
// grid ran as two sequential rounds at 2 waves/SIMD and the per-step LDS
// broadcast latency was exposed (Occupancy 20.6%, 363us). VGPR=104 fits the
// 128-reg budget of 4 waves/SIMD, so full co-residency is free.
__global__ __launch_bounds__(256, 4) void lstm_fused(
    const float* __restrict__ x,
    const float* __restrict__ W_ih,
    const float* __restrict__ W_hh,
    const float* __restrict__ b_ih,
    const float* __restrict__ b_hh,
    const float* __restrict__ W1,
    const float* __restrict__ b1,
    const float* __restrict__ W2,
    const float* __restrict__ b2,
    float* __restrict__ out)
{
    __shared__ __align__(16) float hbuf[4][2][HSZ];
    __shared__ float w1s[64 * 33];   // stride 33: conflict-free MLP reads
    __shared__ float b1s[64];
    __shared__ float w2s[64];

    const int tid  = threadIdx.x;
    const int wave = tid >> 6;
    const int lane = tid & 63;
    const int half = (lane >> 5) & 1;
    const int j    = lane & 31;

    // Stage MLP weights (blockwide, once).
    for (int idx = tid; idx < 64 * HSZ; idx += 256) {
        const int u = idx >> 5, k = idx & 31;
        w1s[u * 33 + k] = W1[idx];
    }
    if (tid < 64) { b1s[tid] = b1[tid]; w2s[tid] = W2[tid]; }
    __syncthreads();

    const int elem = blockIdx.x * 8 + wave * 2 + half;

    // Per-lane weight rows (gate order: i, f, g, o -> row = q*32 + j).
    float Wih[4][ISZ];
    float Whh[4][HSZ];
    float bias[4];
    #pragma unroll
    for (int q = 0; q < 4; ++q) {
        const int row = q * HSZ + j;
        #pragma unroll
        for (int k = 0; k < ISZ; ++k) Wih[q][k] = W_ih[row * ISZ + k];
        #pragma unroll
        for (int k = 0; k < HSZ; ++k) Whh[q][k] = W_hh[row * HSZ + k];
        bias[q] = b_ih[row] + b_hh[row];
    }

    float h = 0.0f, c = 0.0f;
    const float* xp = x + (size_t)elem * (TSTEPS * ISZ);

    // x prefetch (8B-aligned: step offset is a 24B multiple).
    float2 xc0 = *(const float2*)(xp + 0);
    float2 xc1 = *(const float2*)(xp + 2);
    float2 xc2 = *(const float2*)(xp + 4);

    float* hb = &hbuf[wave][half][0];

    for (int t = 0; t < TSTEPS; ++t) {
        // Prefetch next step's x (clamped at the tail; broadcast loads).
        const float* xn = xp + (t + 1 < TSTEPS ? (t + 1) : (TSTEPS - 1)) * ISZ;
        const float2 xn0 = *(const float2*)(xn + 0);
        const float2 xn1 = *(const float2*)(xn + 2);
        const float2 xn2 = *(const float2*)(xn + 4);

        // Broadcast h across the half-wave via LDS (wave-synchronous).
        hb[j] = h;
        __builtin_amdgcn_wave_barrier();

        float acc0 = bias[0], acc1 = bias[1], acc2 = bias[2], acc3 = bias[3];

        const float xv[ISZ] = {xc0.x, xc0.y, xc1.x, xc1.y, xc2.x, xc2.y};
        #pragma unroll
        for (int k = 0; k < ISZ; ++k) {
            acc0 = fmaf(Wih[0][k], xv[k], acc0);
            acc1 = fmaf(Wih[1][k], xv[k], acc1);
            acc2 = fmaf(Wih[2][k], xv[k], acc2);
            acc3 = fmaf(Wih[3][k], xv[k], acc3);
        }

        #pragma unroll
        for (int r = 0; r < 8; ++r) {
            const float4 hv = *(const float4*)(hb + r * 4);
            const float hk[4] = {hv.x, hv.y, hv.z, hv.w};
            #pragma unroll
            for (int m = 0; m < 4; ++m) {
                acc0 = fmaf(Whh[0][4 * r + m], hk[m], acc0);
                acc1 = fmaf(Whh[1][4 * r + m], hk[m], acc1);
                acc2 = fmaf(Whh[2][4 * r + m], hk[m], acc2);
                acc3 = fmaf(Whh[3][4 * r + m], hk[m], acc3);
            }
        }

        const float ig = fast_sigmoid(acc0);
        const float fg = fast_sigmoid(acc1);
        const float gg = fast_tanh(acc2);
        const float og = fast_sigmoid(acc3);
        c = fmaf(fg, c, ig * gg);
        h = og * fast_tanh(c);

        xc0 = xn0; xc1 = xn1; xc2 = xn2;
    }

    // Publish final h, then the MLP head: lane u (0..63) computes hidden unit u
    // for each of the wave's 2 elements; wave-reduce for the final dot.
    hb[j] = h;
    __builtin_amdgcn_wave_barrier();

    const float b2v = b2[0];
    #pragma unroll
    for (int e = 0; e < 2; ++e) {
        const float* hh = &hbuf[wave][e][0];
        float a = b1s[lane];
        #pragma unroll
        for (int k = 0; k < HSZ; ++k) a = fmaf(w1s[lane * 33 + k], hh[k], a);
        a = fmaxf(a, 0.0f) * w2s[lane];
        #pragma unroll
        for (int off = 32; off > 0; off >>= 1) a += __shfl_xor(a, off, 64);
        if (lane == 0) out[blockIdx.x * 8 + wave * 2 + e] = a + b2v;
    }
}

extern "C" void kernel_launch(void* const* d_in, const int* in_sizes, int n_in,
                              void* d_out, int out_size, void* d_ws, size_t ws_size,
                              hipStream_t stream) {
    const float* x    = (const float*)d_in[0];
    const float* W_ih = (const float*)d_in[1];
    const float* W_hh = (const float*)d_in[2];
    const float* b_ih = (const float*)d_in[3];
    const float* b_hh = (const float*)d_in[4];
    const float* W1   = (const float*)d_in[5];
    const float* b1   = (const float*)d_in[6];
    const float* W2   = (const float*)d_in[7];
    const float* b2   = (const float*)d_in[8];
    float* out = (float*)d_out;

    const int B = in_sizes[0] / (TSTEPS * ISZ);   // 8192
    const int grid = B / 8;                       // 8 elements per 256-thread block

    lstm_fused<<<grid, 256, 0, stream>>>(x, W_ih, W_hh, b_ih, b_hh,
                                         W1, b1, W2, b2, out);
}

// Round 10
// 257.174 us; speedup vs baseline: 7.1961x; 7.1961x over previous
//
#include <hip/hip_runtime.h>
#include <cstdint>

#define HSZ 32
#define TSTEPS 256
#define ISZ 6

typedef _Float16 h2_t __attribute__((ext_vector_type(2)));
typedef _Float16 h8_t __attribute__((ext_vector_type(8)));

// sigmoid(x) = 1/(1+e^-x); tanh(x) = 2*sigmoid(2x)-1. Native v_exp/v_rcp.
__device__ __forceinline__ float fast_sigmoid(float x) {
    return __builtin_amdgcn_rcpf(1.0f + __expf(-x));
}
__device__ __forceinline__ float fast_tanh(float x) {
    return 2.0f * __builtin_amdgcn_rcpf(1.0f + __expf(-2.0f * x)) - 1.0f;
}

// v_dot2_f32_f16: 2 f16 MACs with f32 accumulate. Hedge with a portable
// fallback so compilation cannot fail if the builtin is absent on gfx950.
#if __has_builtin(__builtin_amdgcn_fdot2)
__device__ __forceinline__ float dot2(h2_t a, h2_t b, float acc) {
    return __builtin_amdgcn_fdot2(a, b, acc, false);
}
#else
__device__ __forceinline__ float dot2(h2_t a, h2_t b, float acc) {
    acc = fmaf((float)a.x, (float)b.x, acc);
    return fmaf((float)a.y, (float)b.y, acc);
}
#endif

// Mapping: block = 256 threads = 4 waves; each wave handles 2 batch elements
// (lanes 0-31 -> elem A, lanes 32-63 -> elem B); lane j = hidden unit j, and
// holds its 4 gate rows (i,f,g,o; row = q*32+j) of W_hh/W_ih as PACKED f16
// pairs: 64+12 VGPRs instead of 152 f32. Round-8 post-mortem: f32 weights at
// launch_bounds(256,4) forced VGPR=64 -> per-step scratch spills, 6.8 GB
// FETCH, 1850us. f16 packing makes 4 waves/SIMD fit honestly (~115 VGPRs).
// h is broadcast per step via LDS as f16 (1 ds_write_b16 + 4 ds_read_b128,
// wave-synchronous); c/h state and dot2 accumulation stay f32.
__global__ __launch_bounds__(256, 4) void lstm_fused(
    const float* __restrict__ x,
    const float* __restrict__ W_ih,
    const float* __restrict__ W_hh,
    const float* __restrict__ b_ih,
    const float* __restrict__ b_hh,
    const float* __restrict__ W1,
    const float* __restrict__ b1,
    const float* __restrict__ W2,
    const float* __restrict__ b2,
    float* __restrict__ out)
{
    __shared__ __align__(16) _Float16 hbuf16[4][2][HSZ];  // f16 h broadcast
    __shared__ __align__(16) float hbf[4][2][HSZ];        // f32 h for MLP head
    __shared__ float w1s[64 * 33];   // stride 33: conflict-free MLP reads
    __shared__ float b1s[64];
    __shared__ float w2s[64];

    const int tid  = threadIdx.x;
    const int wave = tid >> 6;
    const int lane = tid & 63;
    const int half = (lane >> 5) & 1;
    const int j    = lane & 31;

    // Stage MLP weights (blockwide, once).
    for (int idx = tid; idx < 64 * HSZ; idx += 256) {
        const int u = idx >> 5, k = idx & 31;
        w1s[u * 33 + k] = W1[idx];
    }
    if (tid < 64) { b1s[tid] = b1[tid]; w2s[tid] = W2[tid]; }
    __syncthreads();

    const int elem = blockIdx.x * 8 + wave * 2 + half;

    // Per-lane packed-f16 weight rows (gate order i,f,g,o -> row = q*32 + j).
    h2_t Whh[4][HSZ / 2];
    h2_t Wih[4][ISZ / 2];
    float bias[4];
    #pragma unroll
    for (int q = 0; q < 4; ++q) {
        const int row = q * HSZ + j;
        const float2* wh = (const float2*)(W_hh + row * HSZ);
        #pragma unroll
        for (int k = 0; k < HSZ / 2; ++k) {
            const float2 w = wh[k];
            Whh[q][k] = h2_t{(_Float16)w.x, (_Float16)w.y};
        }
        const float2* wi = (const float2*)(W_ih + row * ISZ);
        #pragma unroll
        for (int k = 0; k < ISZ / 2; ++k) {
            const float2 w = wi[k];
            Wih[q][k] = h2_t{(_Float16)w.x, (_Float16)w.y};
        }
        bias[q] = b_ih[row] + b_hh[row];
    }

    float h = 0.0f, c = 0.0f;
    const float* xp = x + (size_t)elem * (TSTEPS * ISZ);

    // x prefetch (8B-aligned: step offset is a 24B multiple).
    float2 xc0 = *(const float2*)(xp + 0);
    float2 xc1 = *(const float2*)(xp + 2);
    float2 xc2 = *(const float2*)(xp + 4);

    _Float16* hb = &hbuf16[wave][half][0];

    for (int t = 0; t < TSTEPS; ++t) {
        // Prefetch next step's x (clamped at the tail; broadcast loads).
        const float* xn = xp + (t + 1 < TSTEPS ? (t + 1) : (TSTEPS - 1)) * ISZ;
        const float2 xn0 = *(const float2*)(xn + 0);
        const float2 xn1 = *(const float2*)(xn + 2);
        const float2 xn2 = *(const float2*)(xn + 4);

        // Broadcast h (f16) across the half-wave via LDS (wave-synchronous).
        hb[j] = (_Float16)h;
        __builtin_amdgcn_wave_barrier();

        // Pack current x to f16 pairs.
        const h2_t xv0 = h2_t{(_Float16)xc0.x, (_Float16)xc0.y};
        const h2_t xv1 = h2_t{(_Float16)xc1.x, (_Float16)xc1.y};
        const h2_t xv2 = h2_t{(_Float16)xc2.x, (_Float16)xc2.y};

        float acc0 = bias[0], acc1 = bias[1], acc2 = bias[2], acc3 = bias[3];

        acc0 = dot2(Wih[0][0], xv0, acc0);
        acc1 = dot2(Wih[1][0], xv0, acc1);
        acc2 = dot2(Wih[2][0], xv0, acc2);
        acc3 = dot2(Wih[3][0], xv0, acc3);
        acc0 = dot2(Wih[0][1], xv1, acc0);
        acc1 = dot2(Wih[1][1], xv1, acc1);
        acc2 = dot2(Wih[2][1], xv1, acc2);
        acc3 = dot2(Wih[3][1], xv1, acc3);
        acc0 = dot2(Wih[0][2], xv2, acc0);
        acc1 = dot2(Wih[1][2], xv2, acc1);
        acc2 = dot2(Wih[2][2], xv2, acc2);
        acc3 = dot2(Wih[3][2], xv2, acc3);

        // 4x ds_read_b128: 8 f16 h-values per read, broadcast across lanes.
        // Inner 4 pairs manually unrolled: shufflevector needs literal indices.
        const h8_t* hp = (const h8_t*)hb;
        #pragma unroll
        for (int r = 0; r < 4; ++r) {
            const h8_t blk = hp[r];
            const h2_t hv0 = __builtin_shufflevector(blk, blk, 0, 1);
            const h2_t hv1 = __builtin_shufflevector(blk, blk, 2, 3);
            const h2_t hv2 = __builtin_shufflevector(blk, blk, 4, 5);
            const h2_t hv3 = __builtin_shufflevector(blk, blk, 6, 7);
            const int k = r * 4;
            acc0 = dot2(Whh[0][k + 0], hv0, acc0);
            acc1 = dot2(Whh[1][k + 0], hv0, acc1);
            acc2 = dot2(Whh[2][k + 0], hv0, acc2);
            acc3 = dot2(Whh[3][k + 0], hv0, acc3);
            acc0 = dot2(Whh[0][k + 1], hv1, acc0);
            acc1 = dot2(Whh[1][k + 1], hv1, acc1);
            acc2 = dot2(Whh[2][k + 1], hv1, acc2);
            acc3 = dot2(Whh[3][k + 1], hv1, acc3);
            acc0 = dot2(Whh[0][k + 2], hv2, acc0);
            acc1 = dot2(Whh[1][k + 2], hv2, acc1);
            acc2 = dot2(Whh[2][k + 2], hv2, acc2);
            acc3 = dot2(Whh[3][k + 2], hv2, acc3);
            acc0 = dot2(Whh[0][k + 3], hv3, acc0);
            acc1 = dot2(Whh[1][k + 3], hv3, acc1);
            acc2 = dot2(Whh[2][k + 3], hv3, acc2);
            acc3 = dot2(Whh[3][k + 3], hv3, acc3);
        }

        const float ig = fast_sigmoid(acc0);
        const float fg = fast_sigmoid(acc1);
        const float gg = fast_tanh(acc2);
        const float og = fast_sigmoid(acc3);
        c = fmaf(fg, c, ig * gg);
        h = og * fast_tanh(c);

        xc0 = xn0; xc1 = xn1; xc2 = xn2;
    }

    // Publish final h (f32), then the MLP head: lane u (0..63) computes hidden
    // unit u for each of the wave's 2 elements; wave-reduce for the final dot.
    hbf[wave][half][j] = h;
    __builtin_amdgcn_wave_barrier();

    const float b2v = b2[0];
    #pragma unroll
    for (int e = 0; e < 2; ++e) {
        const float* hh = &hbf[wave][e][0];
        float a = b1s[lane];
        #pragma unroll
        for (int k = 0; k < HSZ; ++k) a = fmaf(w1s[lane * 33 + k], hh[k], a);
        a = fmaxf(a, 0.0f) * w2s[lane];
        #pragma unroll
        for (int off = 32; off > 0; off >>= 1) a += __shfl_xor(a, off, 64);
        if (lane == 0) out[blockIdx.x * 8 + wave * 2 + e] = a + b2v;
    }
}

extern "C" void kernel_launch(void* const* d_in, const int* in_sizes, int n_in,
                              void* d_out, int out_size, void* d_ws, size_t ws_size,
                              hipStream_t stream) {
    const float* x    = (const float*)d_in[0];
    const float* W_ih = (const float*)d_in[1];
    const float* W_hh = (const float*)d_in[2];
    const float* b_ih = (const float*)d_in[3];
    const float* b_hh = (const float*)d_in[4];
    const float* W1   = (const float*)d_in[5];
    const float* b1   = (const float*)d_in[6];
    const float* W2   = (const float*)d_in[7];
    const float* b2   = (const float*)d_in[8];
    float* out = (float*)d_out;

    const int B = in_sizes[0] / (TSTEPS * ISZ);   // 8192
    const int grid = B / 8;                       // 8 elements per 256-thread block

    lstm_fused<<<grid, 256, 0, stream>>>(x, W_ih, W_hh, b_ih, b_hh,
                                         W1, b1, W2, b2, out);
}

// Round 12
// 246.899 us; speedup vs baseline: 7.4955x; 1.0416x over previous
//
#include <hip/hip_runtime.h>
#include <cstdint>

#define HSZ 32
#define TSTEPS 256
#define ISZ 6

typedef _Float16 h2_t __attribute__((ext_vector_type(2)));
typedef _Float16 h4_t __attribute__((ext_vector_type(4)));
typedef _Float16 h8_t __attribute__((ext_vector_type(8)));

// sigmoid(x) = 1/(1+e^-x); tanh(x) = 2*sigmoid(2x)-1. Native v_exp/v_rcp.
__device__ __forceinline__ float fast_sigmoid(float x) {
    return __builtin_amdgcn_rcpf(1.0f + __expf(-x));
}
__device__ __forceinline__ float fast_tanh(float x) {
    return 2.0f * __builtin_amdgcn_rcpf(1.0f + __expf(-2.0f * x)) - 1.0f;
}

// v_dot2_f32_f16: 2 f16 MACs with f32 accumulate (hedged fallback).
#if __has_builtin(__builtin_amdgcn_fdot2)
__device__ __forceinline__ float dot2(h2_t a, h2_t b, float acc) {
    return __builtin_amdgcn_fdot2(a, b, acc, false);
}
#else
__device__ __forceinline__ float dot2(h2_t a, h2_t b, float acc) {
    acc = fmaf((float)a.x, (float)b.x, acc);
    return fmaf((float)a.y, (float)b.y, acc);
}
#endif

// Mapping: block = 256 threads = 4 waves; each wave handles 2 batch elements
// (lanes 0-31 -> elem A, lanes 32-63 -> elem B); lane j = hidden unit j, and
// holds its 4 gate rows (i,f,g,o; row = q*32+j) of W_hh/W_ih as packed f16
// pairs (~76 VGPRs). h is broadcast per step via LDS f16 (1 ds_write_b16 + 4
// broadcast ds_read_b128, wave-synchronous); c/h state + accumulation f32.
//
// Round-10 post-mortem: at (256,4) the per-wave unified budget (512/4=128)
// made the compiler split 64 VGPR + AGPRs (VGPR_Count=64, Occupancy 30.7%,
// real VALU util ~40%) -> stall-bound. (256,3) gives ~170 regs/wave so the
// ~110-reg working set stays pure-VGPR; x is staged to LDS as f16 once
// (coalesced) so the T-loop has no global traffic at all.
__global__ __launch_bounds__(256, 3) void lstm_fused(
    const float* __restrict__ x,
    const float* __restrict__ W_ih,
    const float* __restrict__ W_hh,
    const float* __restrict__ b_ih,
    const float* __restrict__ b_hh,
    const float* __restrict__ W1,
    const float* __restrict__ b1,
    const float* __restrict__ W2,
    const float* __restrict__ b2,
    float* __restrict__ out)
{
    __shared__ __align__(16) h2_t    xs[8 * TSTEPS * 3];  // 12 KB f16 x stage
    __shared__ __align__(16) _Float16 hbuf16[4][2][HSZ];  // f16 h broadcast
    __shared__ __align__(16) float   hbf[4][2][HSZ];      // f32 h for MLP head
    __shared__ float w1s[64 * 33];   // stride 33: conflict-free MLP reads
    __shared__ float b1s[64];
    __shared__ float w2s[64];

    const int tid  = threadIdx.x;
    const int wave = tid >> 6;
    const int lane = tid & 63;
    const int half = (lane >> 5) & 1;
    const int j    = lane & 31;

    // Stage x for this block's 8 elems: 12288 f32 -> f16, fully coalesced.
    {
        const float4* xg = (const float4*)(x + (size_t)blockIdx.x * (8 * TSTEPS * ISZ));
        #pragma unroll
        for (int k = 0; k < 12; ++k) {
            const int i = tid + k * 256;          // float4 index 0..3071
            const float4 v = xg[i];
            h4_t p;
            p.x = (_Float16)v.x; p.y = (_Float16)v.y;
            p.z = (_Float16)v.z; p.w = (_Float16)v.w;
            *(h4_t*)&xs[i * 2] = p;
        }
    }
    // Stage MLP weights (blockwide, once).
    for (int idx = tid; idx < 64 * HSZ; idx += 256) {
        const int u = idx >> 5, k = idx & 31;
        w1s[u * 33 + k] = W1[idx];
    }
    if (tid < 64) { b1s[tid] = b1[tid]; w2s[tid] = W2[tid]; }
    __syncthreads();

    // Per-lane packed-f16 weight rows (gate order i,f,g,o -> row = q*32 + j).
    h2_t Whh[4][HSZ / 2];
    h2_t Wih[4][ISZ / 2];
    float bias[4];
    #pragma unroll
    for (int q = 0; q < 4; ++q) {
        const int row = q * HSZ + j;
        const float2* wh = (const float2*)(W_hh + row * HSZ);
        #pragma unroll
        for (int k = 0; k < HSZ / 2; ++k) {
            const float2 w = wh[k];
            Whh[q][k] = h2_t{(_Float16)w.x, (_Float16)w.y};
        }
        const float2* wi = (const float2*)(W_ih + row * ISZ);
        #pragma unroll
        for (int k = 0; k < ISZ / 2; ++k) {
            const float2 w = wi[k];
            Wih[q][k] = h2_t{(_Float16)w.x, (_Float16)w.y};
        }
        bias[q] = b_ih[row] + b_hh[row];
    }

    float h = 0.0f, c = 0.0f;
    _Float16* hb = &hbuf16[wave][half][0];
    const h2_t* xrow = &xs[(wave * 2 + half) * (TSTEPS * 3)];

    for (int t = 0; t < TSTEPS; ++t) {
        // Broadcast h (f16) across the half-wave via LDS (wave-synchronous).
        hb[j] = (_Float16)h;
        __builtin_amdgcn_wave_barrier();

        // x_t for this elem: 3 h2 from LDS (broadcast within half-wave).
        const h2_t xv0 = xrow[0];
        const h2_t xv1 = xrow[1];
        const h2_t xv2 = xrow[2];
        xrow += 3;

        float acc0 = bias[0], acc1 = bias[1], acc2 = bias[2], acc3 = bias[3];

        acc0 = dot2(Wih[0][0], xv0, acc0);
        acc1 = dot2(Wih[1][0], xv0, acc1);
        acc2 = dot2(Wih[2][0], xv0, acc2);
        acc3 = dot2(Wih[3][0], xv0, acc3);
        acc0 = dot2(Wih[0][1], xv1, acc0);
        acc1 = dot2(Wih[1][1], xv1, acc1);
        acc2 = dot2(Wih[2][1], xv1, acc2);
        acc3 = dot2(Wih[3][1], xv1, acc3);
        acc0 = dot2(Wih[0][2], xv2, acc0);
        acc1 = dot2(Wih[1][2], xv2, acc1);
        acc2 = dot2(Wih[2][2], xv2, acc2);
        acc3 = dot2(Wih[3][2], xv2, acc3);

        // 4x ds_read_b128: 8 f16 h-values per read, broadcast across lanes.
        const h8_t* hp = (const h8_t*)hb;
        #pragma unroll
        for (int r = 0; r < 4; ++r) {
            const h8_t blk = hp[r];
            const h2_t hv0 = __builtin_shufflevector(blk, blk, 0, 1);
            const h2_t hv1 = __builtin_shufflevector(blk, blk, 2, 3);
            const h2_t hv2 = __builtin_shufflevector(blk, blk, 4, 5);
            const h2_t hv3 = __builtin_shufflevector(blk, blk, 6, 7);
            const int k = r * 4;
            acc0 = dot2(Whh[0][k + 0], hv0, acc0);
            acc1 = dot2(Whh[1][k + 0], hv0, acc1);
            acc2 = dot2(Whh[2][k + 0], hv0, acc2);
            acc3 = dot2(Whh[3][k + 0], hv0, acc3);
            acc0 = dot2(Whh[0][k + 1], hv1, acc0);
            acc1 = dot2(Whh[1][k + 1], hv1, acc1);
            acc2 = dot2(Whh[2][k + 1], hv1, acc2);
            acc3 = dot2(Whh[3][k + 1], hv1, acc3);
            acc0 = dot2(Whh[0][k + 2], hv2, acc0);
            acc1 = dot2(Whh[1][k + 2], hv2, acc1);
            acc2 = dot2(Whh[2][k + 2], hv2, acc2);
            acc3 = dot2(Whh[3][k + 2], hv2, acc3);
            acc0 = dot2(Whh[0][k + 3], hv3, acc0);
            acc1 = dot2(Whh[1][k + 3], hv3, acc1);
            acc2 = dot2(Whh[2][k + 3], hv3, acc2);
            acc3 = dot2(Whh[3][k + 3], hv3, acc3);
        }

        const float ig = fast_sigmoid(acc0);
        const float fg = fast_sigmoid(acc1);
        const float gg = fast_tanh(acc2);
        const float og = fast_sigmoid(acc3);
        c = fmaf(fg, c, ig * gg);
        h = og * fast_tanh(c);
    }

    // Publish final h (f32), then the MLP head: lane u (0..63) computes hidden
    // unit u for each of the wave's 2 elements; wave-reduce for the final dot.
    hbf[wave][half][j] = h;
    __builtin_amdgcn_wave_barrier();

    const float b2v = b2[0];
    #pragma unroll
    for (int e = 0; e < 2; ++e) {
        const float* hh = &hbf[wave][e][0];
        float a = b1s[lane];
        #pragma unroll
        for (int k = 0; k < HSZ; ++k) a = fmaf(w1s[lane * 33 + k], hh[k], a);
        a = fmaxf(a, 0.0f) * w2s[lane];
        #pragma unroll
        for (int off = 32; off > 0; off >>= 1) a += __shfl_xor(a, off, 64);
        if (lane == 0) out[blockIdx.x * 8 + wave * 2 + e] = a + b2v;
    }
}

extern "C" void kernel_launch(void* const* d_in, const int* in_sizes, int n_in,
                              void* d_out, int out_size, void* d_ws, size_t ws_size,
                              hipStream_t stream) {
    const float* x    = (const float*)d_in[0];
    const float* W_ih = (const float*)d_in[1];
    const float* W_hh = (const float*)d_in[2];
    const float* b_ih = (const float*)d_in[3];
    const float* b_hh = (const float*)d_in[4];
    const float* W1   = (const float*)d_in[5];
    const float* b1   = (const float*)d_in[6];
    const float* W2   = (const float*)d_in[7];
    const float* b2   = (const float*)d_in[8];
    float* out = (float*)d_out;

    const int B = in_sizes[0] / (TSTEPS * ISZ);   // 8192
    const int grid = B / 8;                       // 8 elements per 256-thread block

    lstm_fused<<<grid, 256, 0, stream>>>(x, W_ih, W_hh, b_ih, b_hh,
                                         W1, b1, W2, b2, out);
}

// Round 14
// 190.349 us; speedup vs baseline: 9.7224x; 1.2971x over previous
//
#include <hip/hip_runtime.h>
#include <cstdint>

#define HSZ 32
#define TSTEPS 256
#define ISZ 6
#define NB 16

typedef _Float16 h8_t __attribute__((ext_vector_type(8)));
typedef float f4_t __attribute__((ext_vector_type(4)));

__device__ __forceinline__ float fast_sigmoid(float x) {
    return __builtin_amdgcn_rcpf(1.0f + __expf(-x));
}
__device__ __forceinline__ float fast_tanh(float x) {
    return 2.0f * __builtin_amdgcn_rcpf(1.0f + __expf(-2.0f * x)) - 1.0f;
}

// MFMA formulation. Block = 512 thr = 8 waves, NB=16 batch elems, grid=512
// (2 blocks/CU). gates[16b x 128g] = [h|x] @ [W_hh|W_ih]^T + bias via
// mfma_f32_16x16x32_f16: wave w owns gate N-tile [16w,16w+16) and holds its
// B-fragments (W rows, f16) + bias in regs for the whole T-loop.
// Fragment layouts (m89-verified C/D; standard A/B):
//   A[m][k]: m=lane&15, k=(lane>>4)*8+i   (8 f16 = 4 VGPR)
//   B[k][n]: n=lane&15, k=(lane>>4)*8+i
//   D[m][n]: n=lane&15, m=(lane>>4)*4+r   (4 f32)
// Per step: 2 MFMAs (x-part K-padded, h-part chained, bias preset in C) ->
// per-tile activation (uniform branch per wave) -> gbuf -> barrier ->
// thread (b=tid&15,u=tid>>4) updates its c (register-resident), writes h f16
// -> barrier -> next A-frag read. Round-12 post-mortem: scalar dot path costs
// ~6-8cyc/2-MAC (fallback or quarter-rate dot) -> structurally ~250us; MFMA
// removes all 152 dot-ops per wave-step.
__global__ __launch_bounds__(512, 4) void lstm_mfma(
    const float* __restrict__ x,
    const float* __restrict__ W_ih,
    const float* __restrict__ W_hh,
    const float* __restrict__ b_ih,
    const float* __restrict__ b_hh,
    const float* __restrict__ W1,
    const float* __restrict__ b1,
    const float* __restrict__ W2,
    const float* __restrict__ b2,
    float* __restrict__ out)
{
    __shared__ __align__(16) float    gbuf[8 * 16 * 17];   // activated gate tiles, pad 17
    __shared__ __align__(16) _Float16 hlds[NB * 40];       // h state f16, row stride 40 (16B-aligned frags)
    __shared__ __align__(16) float    hbf[NB * 33];        // final h f32 for MLP
    __shared__ float w1s[64 * 33];
    __shared__ float b1s[64];
    __shared__ float w2s[64];

    const int tid  = threadIdx.x;
    const int wv   = tid >> 6;      // wave = gate tile index 0..7
    const int lane = tid & 63;
    const int n16  = lane & 15;     // tile col / A row
    const int khi  = lane >> 4;     // k-quad 0..3

    // ---- one-time staging ----
    for (int i = tid; i < 64 * HSZ; i += 512) w1s[(i >> 5) * 33 + (i & 31)] = W1[i];
    if (tid < 64) { b1s[tid] = b1[tid]; w2s[tid] = W2[tid]; }
    if (tid < NB * 40 / 2) ((unsigned int*)hlds)[tid] = 0u;   // zero h0

    // B-fragment: W_hh rows (gate row = 16*wv + n16), k-slice khi*8..+8
    const int grow = 16 * wv + n16;
    h8_t bhh;
    {
        const float4* p = (const float4*)(W_hh + grow * HSZ + khi * 8);
        const float4 a = p[0], b = p[1];
        bhh[0] = (_Float16)a.x; bhh[1] = (_Float16)a.y;
        bhh[2] = (_Float16)a.z; bhh[3] = (_Float16)a.w;
        bhh[4] = (_Float16)b.x; bhh[5] = (_Float16)b.y;
        bhh[6] = (_Float16)b.z; bhh[7] = (_Float16)b.w;
    }
    h8_t bih = {(_Float16)0, (_Float16)0, (_Float16)0, (_Float16)0,
                (_Float16)0, (_Float16)0, (_Float16)0, (_Float16)0};
    if (khi == 0) {
        const float2* p = (const float2*)(W_ih + grow * ISZ);
        const float2 a = p[0], b = p[1], c2 = p[2];
        bih[0] = (_Float16)a.x;  bih[1] = (_Float16)a.y;
        bih[2] = (_Float16)b.x;  bih[3] = (_Float16)b.y;
        bih[4] = (_Float16)c2.x; bih[5] = (_Float16)c2.y;
    }
    const float biasv = b_ih[grow] + b_hh[grow];
    const bool  isg   = (wv == 4 || wv == 5);   // g-gate tiles -> tanh

    // phase-B mapping: thread <-> (batch pb, unit pu); c lives in this lane.
    const int pb = tid & 15;
    const int pu = tid >> 4;              // 0..31
    const int th = pu >> 4;               // tile half (units 0-15 / 16-31)
    const int pn = pu & 15;
    const float* gin = &gbuf[(th * 16 + pb) * 17 + pn];   // i; f/g/o at +2/4/6*272
    _Float16* hw = &hlds[pb * 40 + pu];
    const h8_t* har = (const h8_t*)&hlds[n16 * 40 + khi * 8];

    // x prefetch (quad-0 lanes supply the A_x fragment; others hold zeros)
    const float* xbase = x + (size_t)(blockIdx.x * NB + n16) * (TSTEPS * ISZ);
    float2 x0, x1, x2;
    if (khi == 0) {
        const float2* p = (const float2*)xbase;
        x0 = p[0]; x1 = p[1]; x2 = p[2];
    }

    __syncthreads();

    float c = 0.0f, hlast = 0.0f;

    for (int t = 0; t < TSTEPS; ++t) {
        // ---- phase A: gates = bias + x@Wih^T + h@Whh^T, activate, publish ----
        const h8_t ah = *har;
        h8_t ax = {(_Float16)0, (_Float16)0, (_Float16)0, (_Float16)0,
                   (_Float16)0, (_Float16)0, (_Float16)0, (_Float16)0};
        if (khi == 0) {
            ax[0] = (_Float16)x0.x; ax[1] = (_Float16)x0.y;
            ax[2] = (_Float16)x1.x; ax[3] = (_Float16)x1.y;
            ax[4] = (_Float16)x2.x; ax[5] = (_Float16)x2.y;
            const float2* p = (const float2*)(xbase + (t + 1 < TSTEPS ? t + 1 : TSTEPS - 1) * ISZ);
            x0 = p[0]; x1 = p[1]; x2 = p[2];
        }
        f4_t d = {biasv, biasv, biasv, biasv};
        d = __builtin_amdgcn_mfma_f32_16x16x32_f16(ax, bih, d, 0, 0, 0);
        d = __builtin_amdgcn_mfma_f32_16x16x32_f16(ah, bhh, d, 0, 0, 0);

        f4_t g;
        if (isg) {
            g[0] = fast_tanh(d[0]); g[1] = fast_tanh(d[1]);
            g[2] = fast_tanh(d[2]); g[3] = fast_tanh(d[3]);
        } else {
            g[0] = fast_sigmoid(d[0]); g[1] = fast_sigmoid(d[1]);
            g[2] = fast_sigmoid(d[2]); g[3] = fast_sigmoid(d[3]);
        }
        #pragma unroll
        for (int r = 0; r < 4; ++r)
            gbuf[(wv * 16 + khi * 4 + r) * 17 + n16] = g[r];

        __syncthreads();

        // ---- phase B: c,h update for (pb, pu) ----
        const float iv = gin[0];
        const float fv = gin[2 * 272];
        const float gv = gin[4 * 272];
        const float ov = gin[6 * 272];
        c = fmaf(fv, c, iv * gv);
        const float hn = ov * fast_tanh(c);
        hlast = hn;
        *hw = (_Float16)hn;

        __syncthreads();
    }

    // ---- MLP head ----
    hbf[pb * 33 + pu] = hlast;
    __syncthreads();

    const int mb = tid >> 5;        // batch 0..15 (2 per wave)
    const int mm = lane & 31;       // MLP units mm and mm+32
    float a1 = b1s[mm], a2 = b1s[mm + 32];
    #pragma unroll
    for (int k = 0; k < HSZ; ++k) {
        const float hk = hbf[mb * 33 + k];
        a1 = fmaf(w1s[mm * 33 + k], hk, a1);
        a2 = fmaf(w1s[(mm + 32) * 33 + k], hk, a2);
    }
    float r = fmaxf(a1, 0.0f) * w2s[mm] + fmaxf(a2, 0.0f) * w2s[mm + 32];
    #pragma unroll
    for (int off = 16; off > 0; off >>= 1) r += __shfl_xor(r, off, 64);
    if ((lane & 31) == 0) out[blockIdx.x * NB + mb] = r + b2[0];
}

extern "C" void kernel_launch(void* const* d_in, const int* in_sizes, int n_in,
                              void* d_out, int out_size, void* d_ws, size_t ws_size,
                              hipStream_t stream) {
    const float* x    = (const float*)d_in[0];
    const float* W_ih = (const float*)d_in[1];
    const float* W_hh = (const float*)d_in[2];
    const float* b_ih = (const float*)d_in[3];
    const float* b_hh = (const float*)d_in[4];
    const float* W1   = (const float*)d_in[5];
    const float* b1   = (const float*)d_in[6];
    const float* W2   = (const float*)d_in[7];
    const float* b2   = (const float*)d_in[8];
    float* out = (float*)d_out;

    const int B = in_sizes[0] / (TSTEPS * ISZ);   // 8192
    const int grid = B / NB;                      // 512 blocks of 512 threads

    lstm_mfma<<<grid, 512, 0, stream>>>(x, W_ih, W_hh, b_ih, b_hh,
                                        W1, b1, W2, b2, out);
}

// Round 15
// 160.683 us; speedup vs baseline: 11.5174x; 1.1846x over previous
//
#include <hip/hip_runtime.h>
#include <cstdint>

#define HSZ 32
#define TSTEPS 256
#define ISZ 6
#define NB 16

typedef _Float16 h8_t __attribute__((ext_vector_type(8)));
typedef float f4_t __attribute__((ext_vector_type(4)));

#if __has_builtin(__builtin_amdgcn_exp2f)
__device__ __forceinline__ float exp2_raw(float x) { return __builtin_amdgcn_exp2f(x); }
#else
__device__ __forceinline__ float exp2_raw(float x) { return __expf(0.69314718056f * x); }
#endif

// One wave (64 thr) owns 16 batch elements and the WHOLE recurrence:
// gates[16b x 128g] = [x|h] @ [Wih|Whh]^T + bias via 8 n-tiles x 2 chained
// mfma_f32_16x16x32_f16. With all 8 tiles in one wave, lane (n16,khi) holds
// d[q][r] = gates[batch khi*4+r][unit 16q+n16]; i,f,g,o of one (b,u) are
// q=0/1,2/3,4/5,6/7 -> SAME LANE. c/h update is pure-register; no barriers,
// no cross-wave LDS (round-14's 2.3e7 bank conflicts + 2 syncthreads/step).
// Only LDS per step: h transpose for next A-frag (8 ds_write_b16 + 1
// ds_read_b128, wave-internal). Weights pre-scaled by -log2e (g rows by
// -2log2e) so sigmoid/tanh = rcp(1+exp2(d)) with no per-step muls.
// bih is zero for khi>=1 lanes and k>=6, so ax needs no masking (0*finite=0).
__global__ __launch_bounds__(64, 2) void lstm_wave(
    const float* __restrict__ x,
    const float* __restrict__ W_ih,
    const float* __restrict__ W_hh,
    const float* __restrict__ b_ih,
    const float* __restrict__ b_hh,
    const float* __restrict__ W1,
    const float* __restrict__ b1,
    const float* __restrict__ W2,
    const float* __restrict__ b2,
    float* __restrict__ out)
{
    __shared__ __align__(16) _Float16 hlds[NB][40];   // h state, 80B rows (16B-aligned)
    __shared__ float w1s[64 * 34];                    // stride 34: even (float2) + conflict-free
    __shared__ float b1s[64];
    __shared__ float w2s[64];

    const int lane = threadIdx.x;
    const int n16  = lane & 15;
    const int khi  = lane >> 4;

    // ---- one-time staging ----
    for (int i = lane; i < 64 * HSZ; i += 64) w1s[(i >> 5) * 34 + (i & 31)] = W1[i];
    b1s[lane] = b1[lane];
    w2s[lane] = W2[lane];
    #pragma unroll
    for (int i = 0; i < 5; ++i) ((unsigned int*)hlds)[lane + i * 64] = 0u;  // h0 = 0

    // B-fragments + bias, pre-scaled. Tile q covers gate rows [16q,16q+16):
    // q0,1=i q2,3=f q4,5=g q6,7=o.
    const float LOG2E = 1.44269504f;
    h8_t bhh[8], bih[8];
    f4_t bias4[8];
    #pragma unroll
    for (int q = 0; q < 8; ++q) {
        const int grow = q * 16 + n16;
        const float s = (q == 4 || q == 5) ? (-2.0f * LOG2E) : (-LOG2E);
        const float4* p = (const float4*)(W_hh + grow * HSZ + khi * 8);
        const float4 a = p[0], b = p[1];
        bhh[q][0] = (_Float16)(s * a.x); bhh[q][1] = (_Float16)(s * a.y);
        bhh[q][2] = (_Float16)(s * a.z); bhh[q][3] = (_Float16)(s * a.w);
        bhh[q][4] = (_Float16)(s * b.x); bhh[q][5] = (_Float16)(s * b.y);
        bhh[q][6] = (_Float16)(s * b.z); bhh[q][7] = (_Float16)(s * b.w);
        const float bb = s * (b_ih[grow] + b_hh[grow]);
        bias4[q][0] = bb; bias4[q][1] = bb; bias4[q][2] = bb; bias4[q][3] = bb;
        bih[q][0] = (_Float16)0; bih[q][1] = (_Float16)0;
        bih[q][2] = (_Float16)0; bih[q][3] = (_Float16)0;
        bih[q][4] = (_Float16)0; bih[q][5] = (_Float16)0;
        bih[q][6] = (_Float16)0; bih[q][7] = (_Float16)0;
        if (khi == 0) {
            const float2* pi = (const float2*)(W_ih + grow * ISZ);
            const float2 i0 = pi[0], i1 = pi[1], i2 = pi[2];
            bih[q][0] = (_Float16)(s * i0.x); bih[q][1] = (_Float16)(s * i0.y);
            bih[q][2] = (_Float16)(s * i1.x); bih[q][3] = (_Float16)(s * i1.y);
            bih[q][4] = (_Float16)(s * i2.x); bih[q][5] = (_Float16)(s * i2.y);
        }
    }

    // x stream for batch n16 (all khi lanes load same addr -> broadcast).
    const float* xb = x + (size_t)(blockIdx.x * NB + n16) * (TSTEPS * ISZ);
    float2 xa0 = ((const float2*)xb)[0], xa1 = ((const float2*)xb)[1], xa2 = ((const float2*)xb)[2];
    const float2* pn1 = (const float2*)(xb + ISZ);
    float2 xn0 = pn1[0], xn1 = pn1[1], xn2 = pn1[2];

    float c[2][4] = {{0.f, 0.f, 0.f, 0.f}, {0.f, 0.f, 0.f, 0.f}};

    __builtin_amdgcn_wave_barrier();

    for (int t = 0; t < TSTEPS; ++t) {
        // A-fragments
        const h8_t ah = *(const h8_t*)&hlds[n16][khi * 8];
        h8_t ax;
        ax[0] = (_Float16)xa0.x; ax[1] = (_Float16)xa0.y;
        ax[2] = (_Float16)xa1.x; ax[3] = (_Float16)xa1.y;
        ax[4] = (_Float16)xa2.x; ax[5] = (_Float16)xa2.y;
        ax[6] = (_Float16)0;     ax[7] = (_Float16)0;
        xa0 = xn0; xa1 = xn1; xa2 = xn2;
        const int tn = (t + 2 < TSTEPS) ? (t + 2) : (TSTEPS - 1);
        const float2* pn = (const float2*)(xb + tn * ISZ);
        xn0 = pn[0]; xn1 = pn[1]; xn2 = pn[2];

        // 16 MFMAs: x-part (K-padded, bias preset) then h-part chained.
        f4_t d[8];
        #pragma unroll
        for (int q = 0; q < 8; ++q)
            d[q] = __builtin_amdgcn_mfma_f32_16x16x32_f16(ax, bih[q], bias4[q], 0, 0, 0);
        #pragma unroll
        for (int q = 0; q < 8; ++q)
            d[q] = __builtin_amdgcn_mfma_f32_16x16x32_f16(ah, bhh[q], d[q], 0, 0, 0);

        // lane-local activations + c/h update (batch khi*4+r, unit hh*16+n16)
        #pragma unroll
        for (int hh = 0; hh < 2; ++hh) {
            #pragma unroll
            for (int r = 0; r < 4; ++r) {
                const float iv = __builtin_amdgcn_rcpf(1.0f + exp2_raw(d[0 + hh][r]));
                const float fv = __builtin_amdgcn_rcpf(1.0f + exp2_raw(d[2 + hh][r]));
                const float gv = fmaf(2.0f, __builtin_amdgcn_rcpf(1.0f + exp2_raw(d[4 + hh][r])), -1.0f);
                const float ov = __builtin_amdgcn_rcpf(1.0f + exp2_raw(d[6 + hh][r]));
                c[hh][r] = fmaf(fv, c[hh][r], iv * gv);
                const float th = fmaf(2.0f, __builtin_amdgcn_rcpf(1.0f + exp2_raw(-2.88539008f * c[hh][r])), -1.0f);
                hlds[khi * 4 + r][hh * 16 + n16] = (_Float16)(ov * th);
            }
        }
        __builtin_amdgcn_wave_barrier();
    }

    // ---- MLP head: lane = (batch n16, unit-quarter khi) ----
    __builtin_amdgcn_wave_barrier();
    float hr[32];
    #pragma unroll
    for (int q8 = 0; q8 < 4; ++q8) {
        const h8_t hv = *(const h8_t*)&hlds[n16][q8 * 8];
        #pragma unroll
        for (int e = 0; e < 8; ++e) hr[q8 * 8 + e] = (float)hv[e];
    }
    float rsum = 0.0f;
    #pragma unroll
    for (int u = 0; u < 16; ++u) {
        const int row = khi * 16 + u;
        float a = b1s[row];
        #pragma unroll
        for (int k = 0; k < 32; k += 2) {
            const float2 w = *(const float2*)&w1s[row * 34 + k];
            a = fmaf(w.x, hr[k], a);
            a = fmaf(w.y, hr[k + 1], a);
        }
        rsum = fmaf(fmaxf(a, 0.0f), w2s[row], rsum);
    }
    rsum += __shfl_xor(rsum, 16, 64);
    rsum += __shfl_xor(rsum, 32, 64);
    if (khi == 0) out[blockIdx.x * NB + n16] = rsum + b2[0];
}

extern "C" void kernel_launch(void* const* d_in, const int* in_sizes, int n_in,
                              void* d_out, int out_size, void* d_ws, size_t ws_size,
                              hipStream_t stream) {
    const float* x    = (const float*)d_in[0];
    const float* W_ih = (const float*)d_in[1];
    const float* W_hh = (const float*)d_in[2];
    const float* b_ih = (const float*)d_in[3];
    const float* b_hh = (const float*)d_in[4];
    const float* W1   = (const float*)d_in[5];
    const float* b1   = (const float*)d_in[6];
    const float* W2   = (const float*)d_in[7];
    const float* b2   = (const float*)d_in[8];
    float* out = (float*)d_out;

    const int B = in_sizes[0] / (TSTEPS * ISZ);   // 8192
    const int grid = B / NB;                      // 512 one-wave blocks

    lstm_wave<<<grid, 64, 0, stream>>>(x, W_ih, W_hh, b_ih, b_hh,
                                       W1, b1, W2, b2, out);
}